// Round 1
// baseline (835.703 us; speedup 1.0000x reference)
//
#include <hip/hip_runtime.h>
#include <stdint.h>

#define M_DIM 4096   // BATCH*SEQ
#define N_DIM 16384  // OUT_FEATURES
#define K_DIM 4096   // IN_FEATURES
#define BM 128
#define BN 128
#define BK 32

typedef __attribute__((ext_vector_type(8))) __bf16 bf16x8;
typedef __attribute__((ext_vector_type(4))) float f32x4;

// fp32 -> bf16 bits, round-to-nearest-even
__device__ __forceinline__ unsigned short f2bf(float f) {
    uint32_t u = __builtin_bit_cast(uint32_t, f);
    uint32_t r = (u + 0x7FFFu + ((u >> 16) & 1u)) >> 16;
    return (unsigned short)r;
}

union Pack8 { unsigned short h[8]; uint4 v; };

__device__ __forceinline__ void async_copy16(const void* g, void* l) {
    __builtin_amdgcn_global_load_lds((__attribute__((address_space(1))) void*)(g),
                                     (__attribute__((address_space(3))) void*)(l),
                                     16, 0, 0);
}

// ---------------- phase 0: cast x fp32 -> bf16 ----------------
__global__ __launch_bounds__(256) void cast_x_kernel(const float* __restrict__ x,
                                                     unsigned short* __restrict__ xb,
                                                     int n8) {
    for (int i = blockIdx.x * blockDim.x + threadIdx.x; i < n8;
         i += gridDim.x * blockDim.x) {
        const float4* p = (const float4*)(x + (size_t)i * 8);
        float4 v0 = p[0], v1 = p[1];
        Pack8 o;
        o.h[0] = f2bf(v0.x); o.h[1] = f2bf(v0.y);
        o.h[2] = f2bf(v0.z); o.h[3] = f2bf(v0.w);
        o.h[4] = f2bf(v1.x); o.h[5] = f2bf(v1.y);
        o.h[6] = f2bf(v1.z); o.h[7] = f2bf(v1.w);
        *(uint4*)(xb + (size_t)i * 8) = o.v;
    }
}

// ---------------- phase 1: dequant weights -> bf16 ----------------
__global__ __launch_bounds__(256) void dequant_kernel(const int* __restrict__ stored,
                                                      const int* __restrict__ sign,
                                                      const float* __restrict__ log_min,
                                                      const float* __restrict__ log_max,
                                                      unsigned short* __restrict__ wb,
                                                      int n8) {
    const float lmin = log_min[0];
    const float lrange = log_max[0] - lmin;
    for (int i = blockIdx.x * blockDim.x + threadIdx.x; i < n8;
         i += gridDim.x * blockDim.x) {
        const int4* ps = (const int4*)(stored + (size_t)i * 8);
        const int4* pg = (const int4*)(sign + (size_t)i * 8);
        int4 s0 = ps[0], s1 = ps[1];
        int4 g0 = pg[0], g1 = pg[1];
        int sv[8] = {s0.x, s0.y, s0.z, s0.w, s1.x, s1.y, s1.z, s1.w};
        int gv[8] = {g0.x, g0.y, g0.z, g0.w, g1.x, g1.y, g1.z, g1.w};
        Pack8 o;
#pragma unroll
        for (int j = 0; j < 8; ++j) {
            float nrm = (255.0f - (float)sv[j]) * (1.0f / 254.0f);
            float w = __expf(lmin + nrm * lrange);
            o.h[j] = f2bf(gv[j] ? w : -w);
        }
        *(uint4*)(wb + (size_t)i * 8) = o.v;
    }
}

// ---------------- phase 2: bf16 GEMM (m97 structure) ----------------
// A: [M][K] bf16 (row-major), W: [N][K] bf16 (row-major over K), C: [M][N] fp32
__global__ __launch_bounds__(256) void gemm_kernel(const unsigned short* __restrict__ A,
                                                   const unsigned short* __restrict__ W,
                                                   const float* __restrict__ bias,
                                                   float* __restrict__ C) {
    __shared__ uint4 smA[512];  // 128 rows x 32 cols bf16 = 8 KB
    __shared__ uint4 smB[512];
    const int tid  = threadIdx.x;
    const int wave = tid >> 6;
    const int lane = tid & 63;
    const int wr = wave >> 1;   // wave row in 2x2 wave grid (64x64 out each)
    const int wc = wave & 1;
    const int rowBase = blockIdx.y * BM;
    const int colBase = blockIdx.x * BN;

    const unsigned short* Ab = A + (size_t)rowBase * K_DIM;
    const unsigned short* Wb = W + (size_t)colBase * K_DIM;

    f32x4 acc[4][4] = {};

    for (int k0 = 0; k0 < K_DIM; k0 += BK) {
        // stage 8KB A-tile + 8KB B-tile: chunk c = 16B = row c>>2, k-off (c&3)*8
#pragma unroll
        for (int i = 0; i < 2; ++i) {
            const int c   = wave * 64 + i * 256 + lane;
            const int row = c >> 2;
            const int ko  = (c & 3) * 8;
            async_copy16(Ab + (size_t)row * K_DIM + (k0 + ko),
                         (char*)smA + (size_t)(wave * 64 + i * 256) * 16);
            async_copy16(Wb + (size_t)row * K_DIM + (k0 + ko),
                         (char*)smB + (size_t)(wave * 64 + i * 256) * 16);
        }
        __syncthreads();

        bf16x8 af[4], bfr[4];
#pragma unroll
        for (int m = 0; m < 4; ++m) {
            const int r = wr * 64 + m * 16 + (lane & 15);
            af[m] = __builtin_bit_cast(bf16x8, smA[r * 4 + (lane >> 4)]);
        }
#pragma unroll
        for (int n = 0; n < 4; ++n) {
            const int r = wc * 64 + n * 16 + (lane & 15);
            bfr[n] = __builtin_bit_cast(bf16x8, smB[r * 4 + (lane >> 4)]);
        }
#pragma unroll
        for (int m = 0; m < 4; ++m)
#pragma unroll
            for (int n = 0; n < 4; ++n)
                acc[m][n] = __builtin_amdgcn_mfma_f32_16x16x32_bf16(
                    af[m], bfr[n], acc[m][n], 0, 0, 0);
        __syncthreads();
    }

    // epilogue: D col = lane&15, row = (lane>>4)*4 + r
#pragma unroll
    for (int m = 0; m < 4; ++m) {
        const int grow0 = rowBase + wr * 64 + m * 16 + (lane >> 4) * 4;
#pragma unroll
        for (int n = 0; n < 4; ++n) {
            const int gcol = colBase + wc * 64 + n * 16 + (lane & 15);
            const float bv = bias[gcol];
#pragma unroll
            for (int r = 0; r < 4; ++r)
                C[(size_t)(grow0 + r) * N_DIM + gcol] = acc[m][n][r] + bv;
        }
    }
}

// ---------------- fallback: fused dequant-in-GEMM (if ws too small) ----------------
__global__ __launch_bounds__(256) void gemm_fused_kernel(const float* __restrict__ X,
                                                         const int* __restrict__ stored,
                                                         const int* __restrict__ sign,
                                                         const float* __restrict__ log_min,
                                                         const float* __restrict__ log_max,
                                                         const float* __restrict__ bias,
                                                         float* __restrict__ C) {
    __shared__ uint4 smA[512];
    __shared__ uint4 smB[512];
    const float lmin = log_min[0];
    const float lrange = log_max[0] - lmin;
    const int tid  = threadIdx.x;
    const int wave = tid >> 6;
    const int lane = tid & 63;
    const int wr = wave >> 1;
    const int wc = wave & 1;
    const int rowBase = blockIdx.y * BM;
    const int colBase = blockIdx.x * BN;

    f32x4 acc[4][4] = {};

    for (int k0 = 0; k0 < K_DIM; k0 += BK) {
#pragma unroll
        for (int i = 0; i < 2; ++i) {
            const int c   = wave * 64 + i * 256 + lane;
            const int row = c >> 2;
            const int ko  = (c & 3) * 8;
            const float* pa = X + (size_t)(rowBase + row) * K_DIM + k0 + ko;
            float4 a0 = *(const float4*)pa;
            float4 a1 = *(const float4*)(pa + 4);
            Pack8 oa;
            oa.h[0] = f2bf(a0.x); oa.h[1] = f2bf(a0.y);
            oa.h[2] = f2bf(a0.z); oa.h[3] = f2bf(a0.w);
            oa.h[4] = f2bf(a1.x); oa.h[5] = f2bf(a1.y);
            oa.h[6] = f2bf(a1.z); oa.h[7] = f2bf(a1.w);
            smA[c] = oa.v;
            const int* ps = stored + (size_t)(colBase + row) * K_DIM + k0 + ko;
            const int* pg = sign   + (size_t)(colBase + row) * K_DIM + k0 + ko;
            int4 s0 = *(const int4*)ps, s1 = *(const int4*)(ps + 4);
            int4 g0 = *(const int4*)pg, g1 = *(const int4*)(pg + 4);
            int sv[8] = {s0.x, s0.y, s0.z, s0.w, s1.x, s1.y, s1.z, s1.w};
            int gv[8] = {g0.x, g0.y, g0.z, g0.w, g1.x, g1.y, g1.z, g1.w};
            Pack8 ow;
#pragma unroll
            for (int j = 0; j < 8; ++j) {
                float nrm = (255.0f - (float)sv[j]) * (1.0f / 254.0f);
                float w = __expf(lmin + nrm * lrange);
                ow.h[j] = f2bf(gv[j] ? w : -w);
            }
            smB[c] = ow.v;
        }
        __syncthreads();

        bf16x8 af[4], bfr[4];
#pragma unroll
        for (int m = 0; m < 4; ++m) {
            const int r = wr * 64 + m * 16 + (lane & 15);
            af[m] = __builtin_bit_cast(bf16x8, smA[r * 4 + (lane >> 4)]);
        }
#pragma unroll
        for (int n = 0; n < 4; ++n) {
            const int r = wc * 64 + n * 16 + (lane & 15);
            bfr[n] = __builtin_bit_cast(bf16x8, smB[r * 4 + (lane >> 4)]);
        }
#pragma unroll
        for (int m = 0; m < 4; ++m)
#pragma unroll
            for (int n = 0; n < 4; ++n)
                acc[m][n] = __builtin_amdgcn_mfma_f32_16x16x32_bf16(
                    af[m], bfr[n], acc[m][n], 0, 0, 0);
        __syncthreads();
    }

#pragma unroll
    for (int m = 0; m < 4; ++m) {
        const int grow0 = rowBase + wr * 64 + m * 16 + (lane >> 4) * 4;
#pragma unroll
        for (int n = 0; n < 4; ++n) {
            const int gcol = colBase + wc * 64 + n * 16 + (lane & 15);
            const float bv = bias[gcol];
#pragma unroll
            for (int r = 0; r < 4; ++r)
                C[(size_t)(grow0 + r) * N_DIM + gcol] = acc[m][n][r] + bv;
        }
    }
}

extern "C" void kernel_launch(void* const* d_in, const int* in_sizes, int n_in,
                              void* d_out, int out_size, void* d_ws, size_t ws_size,
                              hipStream_t stream) {
    const float* x       = (const float*)d_in[0];
    const int*   stored  = (const int*)d_in[1];
    const int*   sign    = (const int*)d_in[2];
    const float* log_min = (const float*)d_in[3];
    const float* log_max = (const float*)d_in[4];
    const float* bias    = (const float*)d_in[5];
    float* out = (float*)d_out;

    const size_t needA = (size_t)M_DIM * K_DIM * sizeof(unsigned short);  // 32 MB
    const size_t needW = (size_t)N_DIM * K_DIM * sizeof(unsigned short);  // 128 MB

    dim3 grid(N_DIM / BN, M_DIM / BM);  // (128, 32)

    if (ws_size >= needA + needW) {
        unsigned short* Ab = (unsigned short*)d_ws;
        unsigned short* Wb = (unsigned short*)((char*)d_ws + needA);
        cast_x_kernel<<<2048, 256, 0, stream>>>(x, Ab, (M_DIM * K_DIM) / 8);
        dequant_kernel<<<4096, 256, 0, stream>>>(stored, sign, log_min, log_max, Wb,
                                                 (N_DIM * K_DIM) / 8);
        gemm_kernel<<<grid, 256, 0, stream>>>(Ab, Wb, bias, out);
    } else {
        gemm_fused_kernel<<<grid, 256, 0, stream>>>(x, stored, sign, log_min, log_max,
                                                    bias, out);
    }
}

// Round 2
// 704.051 us; speedup vs baseline: 1.1870x; 1.1870x over previous
//
#include <hip/hip_runtime.h>
#include <stdint.h>

#define M_DIM 4096   // BATCH*SEQ
#define N_DIM 16384  // OUT_FEATURES
#define K_DIM 4096   // IN_FEATURES
#define BM 256
#define BN 256
#define BK 64
#define NT (K_DIM / BK)   // 64 K-tiles

typedef __attribute__((ext_vector_type(8))) __bf16 bf16x8;
typedef __attribute__((ext_vector_type(4))) float f32x4;

// fp32 -> bf16 bits, round-to-nearest-even
__device__ __forceinline__ unsigned short f2bf(float f) {
    uint32_t u = __builtin_bit_cast(uint32_t, f);
    uint32_t r = (u + 0x7FFFu + ((u >> 16) & 1u)) >> 16;
    return (unsigned short)r;
}

union Pack8 { unsigned short h[8]; uint4 v; };

__device__ __forceinline__ void async_copy16(const void* g, void* l) {
    __builtin_amdgcn_global_load_lds((__attribute__((address_space(1))) void*)(g),
                                     (__attribute__((address_space(3))) void*)(l),
                                     16, 0, 0);
}

// ---------------- phase 0: cast x fp32 -> bf16 ----------------
__global__ __launch_bounds__(256) void cast_x_kernel(const float* __restrict__ x,
                                                     unsigned short* __restrict__ xb,
                                                     int n8) {
    for (int i = blockIdx.x * blockDim.x + threadIdx.x; i < n8;
         i += gridDim.x * blockDim.x) {
        const float4* p = (const float4*)(x + (size_t)i * 8);
        float4 v0 = p[0], v1 = p[1];
        Pack8 o;
        o.h[0] = f2bf(v0.x); o.h[1] = f2bf(v0.y);
        o.h[2] = f2bf(v0.z); o.h[3] = f2bf(v0.w);
        o.h[4] = f2bf(v1.x); o.h[5] = f2bf(v1.y);
        o.h[6] = f2bf(v1.z); o.h[7] = f2bf(v1.w);
        *(uint4*)(xb + (size_t)i * 8) = o.v;
    }
}

// ---------------- phase 1: dequant weights -> bf16 ----------------
__global__ __launch_bounds__(256) void dequant_kernel(const int* __restrict__ stored,
                                                      const int* __restrict__ sign,
                                                      const float* __restrict__ log_min,
                                                      const float* __restrict__ log_max,
                                                      unsigned short* __restrict__ wb,
                                                      int n8) {
    const float lmin = log_min[0];
    const float lrange = log_max[0] - lmin;
    for (int i = blockIdx.x * blockDim.x + threadIdx.x; i < n8;
         i += gridDim.x * blockDim.x) {
        const int4* ps = (const int4*)(stored + (size_t)i * 8);
        const int4* pg = (const int4*)(sign + (size_t)i * 8);
        int4 s0 = ps[0], s1 = ps[1];
        int4 g0 = pg[0], g1 = pg[1];
        int sv[8] = {s0.x, s0.y, s0.z, s0.w, s1.x, s1.y, s1.z, s1.w};
        int gv[8] = {g0.x, g0.y, g0.z, g0.w, g1.x, g1.y, g1.z, g1.w};
        Pack8 o;
#pragma unroll
        for (int j = 0; j < 8; ++j) {
            float nrm = (255.0f - (float)sv[j]) * (1.0f / 254.0f);
            float w = __expf(lmin + nrm * lrange);
            o.h[j] = f2bf(gv[j] ? w : -w);
        }
        *(uint4*)(wb + (size_t)i * 8) = o.v;
    }
}

// ---------------- phase 2: 256x256 bf16 GEMM, 4-phase/K-tile, counted vmcnt ----------------
// A: [M][K] bf16, W: [N][K] bf16, C: [M][N] fp32
// LDS (128 KiB dynamic): dbuf d in {0,1}:
//   A half h: d*65536 + h*16384           (128 rows x 64 cols bf16, XOR-swizzled)
//   B half h: d*65536 + 32768 + h*16384
// Swizzle (involution on byte offset within a half): off ^= ((row&7)<<4).
// global_load_lds writes linearly; the global SOURCE is pre-inverse-swizzled (rule #21).
__global__ __launch_bounds__(512, 1) void gemm_kernel(const unsigned short* __restrict__ A,
                                                      const unsigned short* __restrict__ W,
                                                      const float* __restrict__ bias,
                                                      float* __restrict__ C) {
    extern __shared__ char lds[];
    const int tid  = threadIdx.x;
    const int wave = tid >> 6;
    const int lane = tid & 63;
    const int l15  = lane & 15;
    const int l16  = lane >> 4;
    const int wr   = wave >> 2;   // 0..1 -> 128-row band
    const int wc   = wave & 3;    // 0..3 -> 64-col band

    // T1: XCD-aware swizzle. nwg=1024, nwg%8==0. Each XCD gets 128 consecutive wg
    // = 2 full M-rows x all 64 N-cols -> 4 MB A-panel L2-resident per XCD.
    const int bid = blockIdx.x;
    const int wg  = ((bid & 7) << 7) | (bid >> 3);
    const int rowBase = (wg >> 6) * BM;
    const int colBase = (wg & 63) * BN;

    f32x4 acc[8][4] = {};

    // stage one K-tile (A+B, 4 halves, 2 x global_load_lds each) into dbuf d
    auto stage = [&](int t, int d) {
        const int kb = t * BK;
        char* base = lds + d * 65536;
#pragma unroll
        for (int u = 0; u < 4; ++u) {                 // A0, A1, B0, B1
            const unsigned short* g = (u < 2) ? A : W;
            const int rb = ((u < 2) ? rowBase : colBase) + (u & 1) * 128;
            char* hb = base + ((u < 2) ? 0 : 32768) + (u & 1) * 16384;
#pragma unroll
            for (int sub = 0; sub < 2; ++sub) {
                const int Ld   = (sub * 512 + tid) * 16;              // linear dest byte
                const int r    = Ld >> 7;                             // row (128 B/row)
                const int colb = (Ld & 127) ^ ((r & 7) << 4);         // inverse-swz source
                async_copy16(g + (size_t)(rb + r) * K_DIM + kb + (colb >> 1),
                             hb + (sub * 512 + wave * 64) * 16);      // wave-uniform dest
            }
        }
    };

    stage(0, 0);

    for (int t = 0; t < NT; ++t) {
        const int cur = t & 1;
        // issue next tile's 8 loads (its buffer was fully consumed at end of t-1),
        // then counted wait: only tile t's 8 oldest must land; next tile stays in flight.
        if (t + 1 < NT) {
            stage(t + 1, cur ^ 1);
            asm volatile("s_waitcnt vmcnt(8)" ::: "memory");
        } else {
            asm volatile("s_waitcnt vmcnt(0)" ::: "memory");
        }
        __builtin_amdgcn_s_barrier();        // all waves' tile-t loads visible
        asm volatile("" ::: "memory");

        const char* bA  = lds + cur * 65536 + wr * 16384;
        const char* bB  = lds + cur * 65536 + 32768 + (wc >> 1) * 16384;
        const int   brB = (wc & 1) * 64;

        bf16x8 aF[4][2];
        bf16x8 bF[2][2];
#pragma unroll
        for (int q = 0; q < 4; ++q) {         // 4 phases: (m-half, n-half) quadrants
            const int mq = q >> 1, nq = q & 1;
            if (nq == 0) {                    // new m-half: 8 ds_read_b128 (A)
#pragma unroll
                for (int i = 0; i < 4; ++i)
#pragma unroll
                    for (int ks = 0; ks < 2; ++ks) {
                        const int r    = (mq * 4 + i) * 16 + l15;
                        const int colb = (ks * 64 + l16 * 16) ^ ((r & 7) << 4);
                        aF[i][ks] = *(const bf16x8*)(bA + (r << 7) + colb);
                    }
            }
#pragma unroll
            for (int j = 0; j < 2; ++j)       // 4 ds_read_b128 (B)
#pragma unroll
                for (int ks = 0; ks < 2; ++ks) {
                    const int r    = brB + (nq * 2 + j) * 16 + l15;
                    const int colb = (ks * 64 + l16 * 16) ^ ((r & 7) << 4);
                    bF[j][ks] = *(const bf16x8*)(bB + (r << 7) + colb);
                }
            __builtin_amdgcn_s_setprio(1);    // T5: MFMA cluster priority
#pragma unroll
            for (int i = 0; i < 4; ++i)
#pragma unroll
                for (int j = 0; j < 2; ++j)
#pragma unroll
                    for (int ks = 0; ks < 2; ++ks)
                        acc[mq * 4 + i][nq * 2 + j] =
                            __builtin_amdgcn_mfma_f32_16x16x32_bf16(
                                aF[i][ks], bF[j][ks], acc[mq * 4 + i][nq * 2 + j],
                                0, 0, 0);
            __builtin_amdgcn_s_setprio(0);
            asm volatile("" ::: "memory");
            __builtin_amdgcn_s_barrier();     // phase lockstep (no vmem drain)
            asm volatile("" ::: "memory");
        }
    }

    // epilogue: C/D layout col=lane&15, row=(lane>>4)*4+reg (m89/m91-verified)
#pragma unroll
    for (int m = 0; m < 8; ++m) {
        const int grow0 = rowBase + wr * 128 + m * 16 + l16 * 4;
#pragma unroll
        for (int n = 0; n < 4; ++n) {
            const int gcol = colBase + wc * 64 + n * 16 + l15;
            const float bv = bias[gcol];
#pragma unroll
            for (int r4 = 0; r4 < 4; ++r4)
                C[(size_t)(grow0 + r4) * N_DIM + gcol] = acc[m][n][r4] + bv;
        }
    }
}

extern "C" void kernel_launch(void* const* d_in, const int* in_sizes, int n_in,
                              void* d_out, int out_size, void* d_ws, size_t ws_size,
                              hipStream_t stream) {
    const float* x       = (const float*)d_in[0];
    const int*   stored  = (const int*)d_in[1];
    const int*   sign    = (const int*)d_in[2];
    const float* log_min = (const float*)d_in[3];
    const float* log_max = (const float*)d_in[4];
    const float* bias    = (const float*)d_in[5];
    float* out = (float*)d_out;

    unsigned short* Ab = (unsigned short*)d_ws;                         // 32 MB
    unsigned short* Wb = (unsigned short*)((char*)d_ws +
                          (size_t)M_DIM * K_DIM * sizeof(unsigned short)); // +128 MB

    cast_x_kernel<<<2048, 256, 0, stream>>>(x, Ab, (M_DIM * K_DIM) / 8);
    dequant_kernel<<<4096, 256, 0, stream>>>(stored, sign, log_min, log_max, Wb,
                                             (N_DIM * K_DIM) / 8);

    hipFuncSetAttribute((const void*)gemm_kernel,
                        hipFuncAttributeMaxDynamicSharedMemorySize, 131072);
    gemm_kernel<<<dim3((M_DIM / BM) * (N_DIM / BN)), dim3(512), 131072, stream>>>(
        Ab, Wb, bias, out);
}

// Round 3
// 654.092 us; speedup vs baseline: 1.2777x; 1.0764x over previous
//
#include <hip/hip_runtime.h>
#include <stdint.h>

#define M_DIM 4096   // BATCH*SEQ
#define N_DIM 16384  // OUT_FEATURES
#define K_DIM 4096   // IN_FEATURES
#define BM 256
#define BN 256
#define BK 64
#define NT (K_DIM / BK)   // 64 K-tiles

typedef __attribute__((ext_vector_type(8))) __bf16 bf16x8;
typedef __attribute__((ext_vector_type(4))) float f32x4;

// fp32 -> bf16 bits, round-to-nearest-even
__device__ __forceinline__ unsigned short f2bf(float f) {
    uint32_t u = __builtin_bit_cast(uint32_t, f);
    uint32_t r = (u + 0x7FFFu + ((u >> 16) & 1u)) >> 16;
    return (unsigned short)r;
}

union Pack8 { unsigned short h[8]; uint4 v; };

__device__ __forceinline__ void async_copy16(const void* g, void* l) {
    __builtin_amdgcn_global_load_lds((__attribute__((address_space(1))) void*)(g),
                                     (__attribute__((address_space(3))) void*)(l),
                                     16, 0, 0);
}

#define BARRIER() do { asm volatile("" ::: "memory"); \
                       __builtin_amdgcn_s_barrier();  \
                       asm volatile("" ::: "memory"); } while (0)

// ---------------- phase 0: cast x fp32 -> bf16 ----------------
__global__ __launch_bounds__(256) void cast_x_kernel(const float* __restrict__ x,
                                                     unsigned short* __restrict__ xb,
                                                     int n8) {
    for (int i = blockIdx.x * blockDim.x + threadIdx.x; i < n8;
         i += gridDim.x * blockDim.x) {
        const float4* p = (const float4*)(x + (size_t)i * 8);
        float4 v0 = p[0], v1 = p[1];
        Pack8 o;
        o.h[0] = f2bf(v0.x); o.h[1] = f2bf(v0.y);
        o.h[2] = f2bf(v0.z); o.h[3] = f2bf(v0.w);
        o.h[4] = f2bf(v1.x); o.h[5] = f2bf(v1.y);
        o.h[6] = f2bf(v1.z); o.h[7] = f2bf(v1.w);
        *(uint4*)(xb + (size_t)i * 8) = o.v;
    }
}

// ---------------- phase 1: dequant weights -> bf16 ----------------
__global__ __launch_bounds__(256) void dequant_kernel(const int* __restrict__ stored,
                                                      const int* __restrict__ sign,
                                                      const float* __restrict__ log_min,
                                                      const float* __restrict__ log_max,
                                                      unsigned short* __restrict__ wb,
                                                      int n8) {
    const float lmin = log_min[0];
    const float lrange = log_max[0] - lmin;
    for (int i = blockIdx.x * blockDim.x + threadIdx.x; i < n8;
         i += gridDim.x * blockDim.x) {
        const int4* ps = (const int4*)(stored + (size_t)i * 8);
        const int4* pg = (const int4*)(sign + (size_t)i * 8);
        int4 s0 = ps[0], s1 = ps[1];
        int4 g0 = pg[0], g1 = pg[1];
        int sv[8] = {s0.x, s0.y, s0.z, s0.w, s1.x, s1.y, s1.z, s1.w};
        int gv[8] = {g0.x, g0.y, g0.z, g0.w, g1.x, g1.y, g1.z, g1.w};
        Pack8 o;
#pragma unroll
        for (int j = 0; j < 8; ++j) {
            float nrm = (255.0f - (float)sv[j]) * (1.0f / 254.0f);
            float w = __expf(lmin + nrm * lrange);
            o.h[j] = f2bf(gv[j] ? w : -w);
        }
        *(uint4*)(wb + (size_t)i * 8) = o.v;
    }
}

// ---------------- phase 2: 256x256 bf16 GEMM, fine-interleaved 4-phase/K-tile ----------------
// A: [M][K] bf16, W: [N][K] bf16, C: [M][N] fp32
// LDS (128 KiB dynamic): dbuf d in {0,1}: A half h at d*65536 + h*16384
// (128 rows x 64 cols bf16, XOR-swizzled); B half h at d*65536 + 32768 + h*16384.
// Swizzle involution on byte offset within a half: off ^= ((row&7)<<4).
// global_load_lds writes linearly; global SOURCE is pre-inverse-swizzled (rule #21).
//
// Schedule (per K-tile t, buffer c=t&1):
//   top:      vmcnt(4) [tile t landed; t+1's A (4 loads) still in flight]; barrier
//   phase q:  ds_reads quadrant q of c;  stage per plan;  barrier;
//             lgkmcnt(0); sched_barrier; setprio(1); 16 MFMA; setprio(0); barrier
//   stage plan: q0 -> B.h0(t+1) into c^1 ; q1 -> B.h1(t+1) into c^1 ;
//               q3 -> A.h0+A.h1(t+2) into c (freed: all A reads of c complete at
//               phase-2 lgkmcnt(0)+post-MFMA barrier; B reads complete at phase-3's).
__global__ __launch_bounds__(512, 1) void gemm_kernel(const unsigned short* __restrict__ A,
                                                      const unsigned short* __restrict__ W,
                                                      const float* __restrict__ bias,
                                                      float* __restrict__ C) {
    extern __shared__ char lds[];
    const int tid  = threadIdx.x;
    const int wave = tid >> 6;
    const int lane = tid & 63;
    const int l15  = lane & 15;
    const int l16  = lane >> 4;
    const int wr   = wave >> 2;   // 0..1 -> 128-row band
    const int wc   = wave & 3;    // 0..3 -> 64-col band

    // T1: XCD-aware swizzle. nwg=1024 (%8==0); each XCD gets 2 M-rows x all N.
    const int bid = blockIdx.x;
    const int wg  = ((bid & 7) << 7) | (bid >> 3);
    const int rowBase = (wg >> 6) * BM;
    const int colBase = (wg & 63) * BN;

    f32x4 acc[8][4] = {};

    // stage one half-tile u (0=A.h0,1=A.h1,2=B.h0,3=B.h1) of tile t into dbuf d
    auto stage_half = [&](int t, int d, int u) {
        const int kb = t * BK;
        const unsigned short* g = (u < 2) ? A : W;
        const int rb = ((u < 2) ? rowBase : colBase) + (u & 1) * 128;
        char* hb = lds + d * 65536 + ((u < 2) ? 0 : 32768) + (u & 1) * 16384;
#pragma unroll
        for (int sub = 0; sub < 2; ++sub) {
            const int Ld   = (sub * 512 + tid) * 16;              // linear dest byte
            const int r    = Ld >> 7;                             // row (128 B/row)
            const int colb = (Ld & 127) ^ ((r & 7) << 4);         // inverse-swz source
            async_copy16(g + (size_t)(rb + r) * K_DIM + kb + (colb >> 1),
                         hb + (sub * 512 + wave * 64) * 16);      // wave-uniform dest
        }
    };

    // prologue: tile 0 complete (8 loads) + tile 1's A halves (4 loads)
    stage_half(0, 0, 0); stage_half(0, 0, 1);
    stage_half(0, 0, 2); stage_half(0, 0, 3);
    stage_half(1, 1, 0); stage_half(1, 1, 1);

    for (int t = 0; t < NT; ++t) {
        const int c = t & 1;
        if (t + 1 < NT) asm volatile("s_waitcnt vmcnt(4)" ::: "memory");
        else            asm volatile("s_waitcnt vmcnt(0)" ::: "memory");
        BARRIER();
        __builtin_amdgcn_sched_barrier(0);

        const char* bA  = lds + c * 65536 + wr * 16384;
        const char* bB  = lds + c * 65536 + 32768 + (wc >> 1) * 16384;
        const int   brB = (wc & 1) * 64;

        bf16x8 aF[4][2];
        bf16x8 bF[2][2];
#pragma unroll
        for (int q = 0; q < 4; ++q) {
            const int mq = q >> 1, nq = q & 1;
            if (nq == 0) {                    // new m-half: 8 ds_read_b128 (A)
#pragma unroll
                for (int i = 0; i < 4; ++i)
#pragma unroll
                    for (int ks = 0; ks < 2; ++ks) {
                        const int r    = (mq * 4 + i) * 16 + l15;
                        const int colb = (ks * 64 + l16 * 16) ^ ((r & 7) << 4);
                        aF[i][ks] = *(const bf16x8*)(bA + (r << 7) + colb);
                    }
            }
#pragma unroll
            for (int j = 0; j < 2; ++j)       // 4 ds_read_b128 (B)
#pragma unroll
                for (int ks = 0; ks < 2; ++ks) {
                    const int r    = brB + (nq * 2 + j) * 16 + l15;
                    const int colb = (ks * 64 + l16 * 16) ^ ((r & 7) << 4);
                    bF[j][ks] = *(const bf16x8*)(bB + (r << 7) + colb);
                }
            // fine-interleaved staging (T3): one or two half-tiles per phase
            if (q == 0 && t + 1 < NT) stage_half(t + 1, c ^ 1, 2);   // B.h0
            if (q == 1 && t + 1 < NT) stage_half(t + 1, c ^ 1, 3);   // B.h1
            if (q == 3 && t + 2 < NT) {                              // A of t+2 -> freed c
                stage_half(t + 2, c, 0);
                stage_half(t + 2, c, 1);
            }
            BARRIER();
            asm volatile("s_waitcnt lgkmcnt(0)" ::: "memory");
            __builtin_amdgcn_sched_barrier(0);
            __builtin_amdgcn_s_setprio(1);    // T5
#pragma unroll
            for (int i = 0; i < 4; ++i)
#pragma unroll
                for (int j = 0; j < 2; ++j)
#pragma unroll
                    for (int ks = 0; ks < 2; ++ks)
                        acc[mq * 4 + i][nq * 2 + j] =
                            __builtin_amdgcn_mfma_f32_16x16x32_bf16(
                                aF[i][ks], bF[j][ks], acc[mq * 4 + i][nq * 2 + j],
                                0, 0, 0);
            __builtin_amdgcn_s_setprio(0);
            BARRIER();
        }
    }

    // epilogue: C/D layout col=lane&15, row=(lane>>4)*4+reg (m89/m91-verified)
#pragma unroll
    for (int m = 0; m < 8; ++m) {
        const int grow0 = rowBase + wr * 128 + m * 16 + l16 * 4;
#pragma unroll
        for (int n = 0; n < 4; ++n) {
            const int gcol = colBase + wc * 64 + n * 16 + l15;
            const float bv = bias[gcol];
#pragma unroll
            for (int r4 = 0; r4 < 4; ++r4)
                C[(size_t)(grow0 + r4) * N_DIM + gcol] = acc[m][n][r4] + bv;
        }
    }
}

extern "C" void kernel_launch(void* const* d_in, const int* in_sizes, int n_in,
                              void* d_out, int out_size, void* d_ws, size_t ws_size,
                              hipStream_t stream) {
    const float* x       = (const float*)d_in[0];
    const int*   stored  = (const int*)d_in[1];
    const int*   sign    = (const int*)d_in[2];
    const float* log_min = (const float*)d_in[3];
    const float* log_max = (const float*)d_in[4];
    const float* bias    = (const float*)d_in[5];
    float* out = (float*)d_out;

    unsigned short* Ab = (unsigned short*)d_ws;                         // 32 MB
    unsigned short* Wb = (unsigned short*)((char*)d_ws +
                          (size_t)M_DIM * K_DIM * sizeof(unsigned short)); // +128 MB

    cast_x_kernel<<<2048, 256, 0, stream>>>(x, Ab, (M_DIM * K_DIM) / 8);
    dequant_kernel<<<4096, 256, 0, stream>>>(stored, sign, log_min, log_max, Wb,
                                             (N_DIM * K_DIM) / 8);

    hipFuncSetAttribute((const void*)gemm_kernel,
                        hipFuncAttributeMaxDynamicSharedMemorySize, 131072);
    gemm_kernel<<<dim3((M_DIM / BM) * (N_DIM / BN)), dim3(512), 131072, stream>>>(
        Ab, Wb, bias, out);
}